// Round 1
// baseline (3082.517 us; speedup 1.0000x reference)
//
#include <hip/hip_runtime.h>
#include <math.h>

#define KNN_K   5
#define QT      16      // queries per phase-A block
#define NCHUNK  25      // train chunks (candidates per query = NCHUNK*KNN_K = 125)
#define DIM     128
#define NT      256
#define FLT_BIG 3.402823466e38f

// ---------------------------------------------------------------- kernel 0
__global__ void rowsq_kernel(const float* __restrict__ data,
                             float* __restrict__ out, int rows) {
    int r = blockIdx.x * blockDim.x + threadIdx.x;
    if (r >= rows) return;
    const float4* p = (const float4*)(data + (size_t)r * DIM);
    float s0 = 0.f, s1 = 0.f, s2 = 0.f, s3 = 0.f;
#pragma unroll
    for (int i = 0; i < DIM / 4; ++i) {
        float4 v = p[i];
        s0 += v.x * v.x; s1 += v.y * v.y; s2 += v.z * v.z; s3 += v.w * v.w;
    }
    out[r] = (s0 + s1) + (s2 + s3);
}

// Static-index top-5 insertion (keeps bd*/bi* in registers; dynamic-index
// array insertion would force scratch spills).
#define TOP5_INSERT(v, id)                                                  \
    if ((v) < bd4) {                                                        \
        bool l0 = (v) < bd0, l1 = (v) < bd1, l2 = (v) < bd2, l3 = (v) < bd3;\
        if (l3) { bd4 = bd3; bi4 = bi3; } else { bd4 = (v); bi4 = (id); }   \
        if (l2) { bd3 = bd2; bi3 = bi2; } else if (l3) { bd3 = (v); bi3 = (id); } \
        if (l1) { bd2 = bd1; bi2 = bi1; } else if (l2) { bd2 = (v); bi2 = (id); } \
        if (l0) { bd1 = bd0; bi1 = bi0; } else if (l1) { bd1 = (v); bi1 = (id); } \
        if (l0) { bd0 = (v); bi0 = (id); }                                  \
    }

// ---------------------------------------------------------------- phase A
// grid = (B/QT, NCHUNK), block = 256. Exact fp32 d2 = x2 - 2*dot + t2;
// per-thread register top-5 over its strided points, LDS merge to per-chunk
// top-5, written to candidate buffers.
__global__ __launch_bounds__(NT) void knn_phaseA(
        const float* __restrict__ x, const float* __restrict__ train,
        const float* __restrict__ x2, const float* __restrict__ t2,
        float* __restrict__ cand_d, int* __restrict__ cand_i,
        int N, int chunkSize) {
    __shared__ float xs[QT][DIM + 4];      // +4 pad: breaks bank conflicts, keeps 16B align
    __shared__ float rd[QT][16 * KNN_K];
    __shared__ int   ri[QT][16 * KNN_K];

    const int q0 = blockIdx.x * QT;
    const int chunk = blockIdx.y;
    const int n0 = chunk * chunkSize;
    const int n1 = min(n0 + chunkSize, N);
    const int t = threadIdx.x;

    for (int i = t; i < QT * DIM; i += NT) {
        int q = i >> 7;            // DIM = 128
        int d = i & (DIM - 1);
        xs[q][d] = x[(size_t)(q0 + q) * DIM + d];
    }
    __syncthreads();

    const int q  = t & (QT - 1);   // 0..15: query within tile
    const int ln = t >> 4;         // 0..15: point lane
    const float myx2 = x2[q0 + q];
    const float4* xp = (const float4*)xs[q];

    float bd0 = FLT_BIG, bd1 = FLT_BIG, bd2 = FLT_BIG, bd3 = FLT_BIG, bd4 = FLT_BIG;
    int   bi0 = -1, bi1 = -1, bi2 = -1, bi3 = -1, bi4 = -1;

    int n = n0 + ln;
    // 4 points per thread per pass: 1 LDS b128 read amortized over 16 FMAs
    for (; n + 48 < n1; n += 64) {
        const float4* r0 = (const float4*)(train + (size_t)n * DIM);
        const float4* r1 = (const float4*)(train + (size_t)(n + 16) * DIM);
        const float4* r2 = (const float4*)(train + (size_t)(n + 32) * DIM);
        const float4* r3 = (const float4*)(train + (size_t)(n + 48) * DIM);
        float dA = 0.f, dB = 0.f, dC = 0.f, dD = 0.f;
#pragma unroll 8
        for (int i = 0; i < DIM / 4; ++i) {
            float4 a = xp[i];
            float4 b0 = r0[i], b1 = r1[i], b2 = r2[i], b3 = r3[i];
            dA += a.x * b0.x + a.y * b0.y + a.z * b0.z + a.w * b0.w;
            dB += a.x * b1.x + a.y * b1.y + a.z * b1.z + a.w * b1.w;
            dC += a.x * b2.x + a.y * b2.y + a.z * b2.z + a.w * b2.w;
            dD += a.x * b3.x + a.y * b3.y + a.z * b3.z + a.w * b3.w;
        }
        float vA = myx2 - 2.f * dA + t2[n];
        float vB = myx2 - 2.f * dB + t2[n + 16];
        float vC = myx2 - 2.f * dC + t2[n + 32];
        float vD = myx2 - 2.f * dD + t2[n + 48];
        TOP5_INSERT(vA, n);
        TOP5_INSERT(vB, n + 16);
        TOP5_INSERT(vC, n + 32);
        TOP5_INSERT(vD, n + 48);
    }
    for (; n < n1; n += 16) {
        const float4* r0 = (const float4*)(train + (size_t)n * DIM);
        float dA = 0.f;
#pragma unroll 8
        for (int i = 0; i < DIM / 4; ++i) {
            float4 a = xp[i], b0 = r0[i];
            dA += a.x * b0.x + a.y * b0.y + a.z * b0.z + a.w * b0.w;
        }
        float vA = myx2 - 2.f * dA + t2[n];
        TOP5_INSERT(vA, n);
    }

    // merge 16 per-thread top-5s -> chunk top-5 per query
    rd[q][ln * KNN_K + 0] = bd0;  ri[q][ln * KNN_K + 0] = bi0;
    rd[q][ln * KNN_K + 1] = bd1;  ri[q][ln * KNN_K + 1] = bi1;
    rd[q][ln * KNN_K + 2] = bd2;  ri[q][ln * KNN_K + 2] = bi2;
    rd[q][ln * KNN_K + 3] = bd3;  ri[q][ln * KNN_K + 3] = bi3;
    rd[q][ln * KNN_K + 4] = bd4;  ri[q][ln * KNN_K + 4] = bi4;
    __syncthreads();

    if (t < QT) {
        float* dq = rd[t];
        int*   iq = ri[t];
        size_t base = ((size_t)(q0 + t) * NCHUNK + chunk) * KNN_K;
#pragma unroll
        for (int k = 0; k < KNN_K; ++k) {
            float best = FLT_BIG; int bj = 0;
            for (int j = 0; j < 16 * KNN_K; ++j) {
                float v = dq[j];
                if (v < best) { best = v; bj = j; }
            }
            cand_d[base + k] = best;
            cand_i[base + k] = iq[bj];
            dq[bj] = FLT_BIG;
        }
    }
}

// ---------------------------------------------------------------- phase B
// One thread per query: merge NCHUNK*5 candidates -> global top-5, then
// inverse-distance weighted label average (with the exact-match/inf branch).
__global__ void knn_phaseB(const float* __restrict__ cand_d,
                           const int* __restrict__ cand_i,
                           const float* __restrict__ labels,
                           float* __restrict__ out, int B, int ncand) {
    int qq = blockIdx.x * blockDim.x + threadIdx.x;
    if (qq >= B) return;
    const float* cd = cand_d + (size_t)qq * ncand;
    const int*   ci = cand_i + (size_t)qq * ncand;

    float bd0 = FLT_BIG, bd1 = FLT_BIG, bd2 = FLT_BIG, bd3 = FLT_BIG, bd4 = FLT_BIG;
    int   bi0 = -1, bi1 = -1, bi2 = -1, bi3 = -1, bi4 = -1;
    for (int j = 0; j < ncand; ++j) {
        float v = cd[j];
        int   id = ci[j];
        TOP5_INSERT(v, id);
    }

    float d0 = sqrtf(fmaxf(bd0, 0.f));
    float d1 = sqrtf(fmaxf(bd1, 0.f));
    float d2 = sqrtf(fmaxf(bd2, 0.f));
    float d3 = sqrtf(fmaxf(bd3, 0.f));
    float d4 = sqrtf(fmaxf(bd4, 0.f));
    bool zero = (d0 == 0.f) || (d1 == 0.f) || (d2 == 0.f) || (d3 == 0.f) || (d4 == 0.f);
    float w0, w1, w2, w3, w4;
    if (zero) {
        w0 = (d0 == 0.f) ? 1.f : 0.f;
        w1 = (d1 == 0.f) ? 1.f : 0.f;
        w2 = (d2 == 0.f) ? 1.f : 0.f;
        w3 = (d3 == 0.f) ? 1.f : 0.f;
        w4 = (d4 == 0.f) ? 1.f : 0.f;
    } else {
        w0 = 1.f / d0; w1 = 1.f / d1; w2 = 1.f / d2; w3 = 1.f / d3; w4 = 1.f / d4;
    }
    float wsum = w0 + w1 + w2 + w3 + w4;
    float lsum = w0 * labels[bi0] + w1 * labels[bi1] + w2 * labels[bi2]
               + w3 * labels[bi3] + w4 * labels[bi4];
    out[qq] = lsum / wsum;
}

// ---------------------------------------------------------------- launch
extern "C" void kernel_launch(void* const* d_in, const int* in_sizes, int n_in,
                              void* d_out, int out_size, void* d_ws, size_t ws_size,
                              hipStream_t stream) {
    const float* x      = (const float*)d_in[0];   // [B, D] fp32
    const float* train  = (const float*)d_in[1];   // [N, D] fp32
    const float* labels = (const float*)d_in[2];   // [N]    fp32

    const int N = in_sizes[2];
    const int D = in_sizes[1] / N;   // 128
    const int B = in_sizes[0] / D;   // 2048
    (void)D; (void)n_in; (void)ws_size;

    // workspace layout (all fully written before read)
    float* t2     = (float*)d_ws;                         // N floats
    float* x2v    = t2 + N;                               // B floats
    float* cand_d = x2v + B;                              // B*NCHUNK*K floats
    int*   cand_i = (int*)(cand_d + (size_t)B * NCHUNK * KNN_K);

    rowsq_kernel<<<(N + NT - 1) / NT, NT, 0, stream>>>(train, t2, N);
    rowsq_kernel<<<(B + NT - 1) / NT, NT, 0, stream>>>(x, x2v, B);

    const int chunkSize = (N + NCHUNK - 1) / NCHUNK;      // 4000
    dim3 gridA(B / QT, NCHUNK);
    knn_phaseA<<<gridA, NT, 0, stream>>>(x, train, x2v, t2,
                                         cand_d, cand_i, N, chunkSize);

    knn_phaseB<<<(B + NT - 1) / NT, NT, 0, stream>>>(cand_d, cand_i, labels,
                                                     (float*)d_out, B,
                                                     NCHUNK * KNN_K);
}

// Round 2
// 310.248 us; speedup vs baseline: 9.9357x; 9.9357x over previous
//
#include <hip/hip_runtime.h>
#include <math.h>

typedef __attribute__((ext_vector_type(8))) short bf16x8;
typedef __attribute__((ext_vector_type(4))) float f32x4;
typedef unsigned short ushortT;

#define KNN_K   5
#define DIM     128
#define FLT_BIG 3.402823466e38f

// ---------------- MFMA-path constants (fixed problem shape) ----------------
#define MF_B     2048
#define MF_N     100000
#define MF_QPB   256              // queries per block (4 waves x 64)
#define MF_QPW   64               // queries per wave
#define MF_NCH   125              // train chunks
#define MF_CHS   800              // rows per chunk (125*800 = 100000, all full)
#define MF_TILES (MF_CHS / 16)    // 50 MFMA row-tiles per chunk
#define MF_CSLOT 6                // candidates kept per (query, chunk)
#define MF_NCAND (MF_NCH * MF_CSLOT)   // 750 candidates per query

// Static-index top-5 insertion (named registers, no scratch spills).
#define TOP5_INSERT(v, id)                                                  \
    if ((v) < bd4) {                                                        \
        bool l0 = (v) < bd0, l1 = (v) < bd1, l2 = (v) < bd2, l3 = (v) < bd3;\
        if (l3) { bd4 = bd3; bi4 = bi3; } else { bd4 = (v); bi4 = (id); }   \
        if (l2) { bd3 = bd2; bi3 = bi2; } else if (l3) { bd3 = (v); bi3 = (id); } \
        if (l1) { bd2 = bd1; bi2 = bi1; } else if (l2) { bd2 = (v); bi2 = (id); } \
        if (l0) { bd1 = bd0; bi1 = bi0; } else if (l1) { bd1 = (v); bi1 = (id); } \
        if (l0) { bd0 = (v); bi0 = (id); }                                  \
    }

// ---------------------------------------------------------------- helpers
__device__ __forceinline__ ushortT f2bf(float f) {
    unsigned u = __float_as_uint(f);
    u += 0x7fffu + ((u >> 16) & 1u);   // RTNE
    return (ushortT)(u >> 16);
}

// fp32 -> bf16 elementwise (4 elems/thread, coalesced both sides)
__global__ void cvt_bf16_kernel(const float* __restrict__ in,
                                ushortT* __restrict__ out, int n) {
    int i = (blockIdx.x * blockDim.x + threadIdx.x) * 4;
    if (i + 3 >= n && i >= n) return;
    float4 v = *(const float4*)(in + i);
    ushort4 o;
    o.x = f2bf(v.x); o.y = f2bf(v.y); o.z = f2bf(v.z); o.w = f2bf(v.w);
    *(ushort4*)(out + i) = o;
}

// per-row squared norm (D = 128)
__global__ void rowsq_kernel(const float* __restrict__ data,
                             float* __restrict__ out, int rows) {
    int r = blockIdx.x * blockDim.x + threadIdx.x;
    if (r >= rows) return;
    const float4* p = (const float4*)(data + (size_t)r * DIM);
    float s0 = 0.f, s1 = 0.f, s2 = 0.f, s3 = 0.f;
#pragma unroll
    for (int i = 0; i < DIM / 4; ++i) {
        float4 v = p[i];
        s0 += v.x * v.x; s1 += v.y * v.y; s2 += v.z * v.z; s3 += v.w * v.w;
    }
    out[r] = (s0 + s1) + (s2 + s3);
}

// ---------------------------------------------------------------- phase A
// grid = (MF_B/MF_QPB, MF_NCH), block = 256 (4 waves).
// Wave holds 64 queries as MFMA B-fragments in registers; streams 16-row
// train tiles as A-fragments direct from global (bf16, L2/L3-resident).
// D = A(train) x B(queries): col = lane&15 = query, row = quad*4+reg = train
// (HW-verified layout, m89/m91). Per-lane top-4 list per query-tile; merged
// via LDS to per-(query,chunk) top-6 candidates keyed by t2 - 2*dot.
__global__ __launch_bounds__(256) void knn_mfma(
        const ushortT* __restrict__ xbf, const ushortT* __restrict__ tbf,
        const float* __restrict__ t2,
        float* __restrict__ cand_d, int* __restrict__ cand_i) {
    __shared__ float sk[4][MF_QPW][16];
    __shared__ int   si[4][MF_QPW][16];

    const int tid  = threadIdx.x;
    const int wv   = tid >> 6;
    const int lane = tid & 63;
    const int quad = lane >> 4;
    const int c16  = lane & 15;
    const int qbase = blockIdx.x * MF_QPB + wv * MF_QPW;
    const int n0 = blockIdx.y * MF_CHS;

    // B-fragments: 64 queries x K=128, loaded once. bq[qtile][kstep]
    bf16x8 bq[4][4];
#pragma unroll
    for (int t = 0; t < 4; ++t)
#pragma unroll
        for (int s = 0; s < 4; ++s)
            bq[t][s] = *(const bf16x8*)(xbf + (size_t)(qbase + t * 16 + c16) * DIM
                                        + s * 32 + quad * 8);

    // per-lane top-4 list per query-tile (query = qbase + t*16 + c16 fixed)
    float lk[4][4]; int li[4][4];
#pragma unroll
    for (int t = 0; t < 4; ++t)
#pragma unroll
        for (int r = 0; r < 4; ++r) { lk[t][r] = FLT_BIG; li[t][r] = 0; }

    const ushortT* ap = tbf + (size_t)(n0 + c16) * DIM + quad * 8;
    const float*   tp = t2 + n0 + quad * 4;

    // software prefetch: A-frags + t2 for tile 0
    bf16x8 fa[4];
#pragma unroll
    for (int s = 0; s < 4; ++s) fa[s] = *(const bf16x8*)(ap + s * 32);
    float4 tv = *(const float4*)tp;

    for (int tile = 0; tile < MF_TILES; ++tile) {
        const int nx = (tile + 1 < MF_TILES) ? tile + 1 : 0;  // clamp: harmless reload
        const ushortT* np = ap + (size_t)nx * (16 * DIM);
        bf16x8 fb[4];
#pragma unroll
        for (int s = 0; s < 4; ++s) fb[s] = *(const bf16x8*)(np + s * 32);
        float4 tn = *(const float4*)(tp + nx * 16);

        f32x4 acc[4];
#pragma unroll
        for (int t = 0; t < 4; ++t) acc[t] = (f32x4){0.f, 0.f, 0.f, 0.f};
#pragma unroll
        for (int s = 0; s < 4; ++s)
#pragma unroll
            for (int t = 0; t < 4; ++t)
                acc[t] = __builtin_amdgcn_mfma_f32_16x16x32_bf16(
                             fa[s], bq[t][s], acc[t], 0, 0, 0);

        const int rowb = n0 + tile * 16 + quad * 4;
        float t2r[4] = {tv.x, tv.y, tv.z, tv.w};
#pragma unroll
        for (int t = 0; t < 4; ++t) {
#pragma unroll
            for (int r = 0; r < 4; ++r) {
                float key = fmaf(-2.f, acc[t][r], t2r[r]);  // t2 - 2*dot
                int   id  = rowb + r;
                if (key < lk[t][3]) {
                    if (key < lk[t][2]) {
                        lk[t][3] = lk[t][2]; li[t][3] = li[t][2];
                        if (key < lk[t][1]) {
                            lk[t][2] = lk[t][1]; li[t][2] = li[t][1];
                            if (key < lk[t][0]) {
                                lk[t][1] = lk[t][0]; li[t][1] = li[t][0];
                                lk[t][0] = key; li[t][0] = id;
                            } else { lk[t][1] = key; li[t][1] = id; }
                        } else { lk[t][2] = key; li[t][2] = id; }
                    } else { lk[t][3] = key; li[t][3] = id; }
                }
            }
        }
#pragma unroll
        for (int s = 0; s < 4; ++s) fa[s] = fb[s];
        tv = tn;
    }

    // merge: 4 quads x top-4 = 16 candidates per query -> top-6 -> global
#pragma unroll
    for (int t = 0; t < 4; ++t)
#pragma unroll
        for (int r = 0; r < 4; ++r) {
            sk[wv][t * 16 + c16][quad * 4 + r] = lk[t][r];
            si[wv][t * 16 + c16][quad * 4 + r] = li[t][r];
        }
    __syncthreads();

    const int mw = tid >> 6, ml = tid & 63;   // thread handles query `tid` of block
    float k6[6]; int i6[6];
#pragma unroll
    for (int j = 0; j < 6; ++j) { k6[j] = FLT_BIG; i6[j] = 0; }
#pragma unroll
    for (int j = 0; j < 16; ++j) {
        float k = sk[mw][ml][j]; int id = si[mw][ml][j];
        if (k < k6[5]) {
            if (k < k6[4]) { k6[5] = k6[4]; i6[5] = i6[4];
                if (k < k6[3]) { k6[4] = k6[3]; i6[4] = i6[3];
                    if (k < k6[2]) { k6[3] = k6[2]; i6[3] = i6[2];
                        if (k < k6[1]) { k6[2] = k6[1]; i6[2] = i6[1];
                            if (k < k6[0]) { k6[1] = k6[0]; i6[1] = i6[0];
                                k6[0] = k; i6[0] = id;
                            } else { k6[1] = k; i6[1] = id; }
                        } else { k6[2] = k; i6[2] = id; }
                    } else { k6[3] = k; i6[3] = id; }
                } else { k6[4] = k; i6[4] = id; }
            } else { k6[5] = k; i6[5] = id; }
        }
    }
    const size_t base = ((size_t)(blockIdx.x * MF_QPB + tid) * MF_NCH + blockIdx.y)
                        * MF_CSLOT;
#pragma unroll
    for (int j = 0; j < 6; ++j) { cand_d[base + j] = k6[j]; cand_i[base + j] = i6[j]; }
}

// ---------------------------------------------------------------- phase B
// One wave per query: top-16 of 750 bf16-keyed candidates via threshold
// scan (no dynamic register indexing), exact fp32 rescore (sum of squared
// diffs, wave-parallel), exact top-5, inverse-distance weighted average.
__global__ __launch_bounds__(64) void knn_final(
        const float* __restrict__ cand_d, const int* __restrict__ cand_i,
        const float* __restrict__ x, const float* __restrict__ train,
        const float* __restrict__ labels, float* __restrict__ out) {
    const int q = blockIdx.x;
    const int lane = threadIdx.x;
    const float xa = x[(size_t)q * DIM + lane];
    const float xb = x[(size_t)q * DIM + 64 + lane];

    float ck[12]; int ci[12];
    const size_t cb = (size_t)q * MF_NCAND;
#pragma unroll
    for (int j = 0; j < 12; ++j) {
        int p = lane + 64 * j;
        if (p < MF_NCAND) { ck[j] = cand_d[cb + p]; ci[j] = cand_i[cb + p]; }
        else { ck[j] = FLT_BIG; ci[j] = 0x7fffffff; }
    }

    float bd0 = FLT_BIG, bd1 = FLT_BIG, bd2 = FLT_BIG, bd3 = FLT_BIG, bd4 = FLT_BIG;
    int   bi0 = 0, bi1 = 0, bi2 = 0, bi3 = 0, bi4 = 0;
    float tk = -FLT_BIG; int ti = -2147483647 - 1;

    for (int round = 0; round < 16; ++round) {
        // lexicographic min over candidates strictly greater than (tk, ti)
        float mk = FLT_BIG; int mi = 0x7fffffff;
#pragma unroll
        for (int j = 0; j < 12; ++j) {
            bool gt = (ck[j] > tk) || (ck[j] == tk && ci[j] > ti);
            if (gt && ((ck[j] < mk) || (ck[j] == mk && ci[j] < mi))) {
                mk = ck[j]; mi = ci[j];
            }
        }
#pragma unroll
        for (int off = 32; off; off >>= 1) {
            float ok = __shfl_xor(mk, off);
            int   oi = __shfl_xor(mi, off);
            if (ok < mk || (ok == mk && oi < mi)) { mk = ok; mi = oi; }
        }
        tk = mk; ti = mi;
        // exact fp32 rescore: d2 = sum (x - t)^2, butterfly sum (all lanes same)
        const float* tr = train + (size_t)mi * DIM;
        float da = xa - tr[lane];
        float db = xb - tr[64 + lane];
        float d2 = fmaf(da, da, db * db);
#pragma unroll
        for (int off = 32; off; off >>= 1) d2 += __shfl_xor(d2, off);
        TOP5_INSERT(d2, mi);
    }

    float d0 = sqrtf(fmaxf(bd0, 0.f));
    float d1 = sqrtf(fmaxf(bd1, 0.f));
    float d2_ = sqrtf(fmaxf(bd2, 0.f));
    float d3 = sqrtf(fmaxf(bd3, 0.f));
    float d4 = sqrtf(fmaxf(bd4, 0.f));
    bool zero = (d0 == 0.f) || (d1 == 0.f) || (d2_ == 0.f) || (d3 == 0.f) || (d4 == 0.f);
    float w0, w1, w2, w3, w4;
    if (zero) {
        w0 = (d0 == 0.f) ? 1.f : 0.f;
        w1 = (d1 == 0.f) ? 1.f : 0.f;
        w2 = (d2_ == 0.f) ? 1.f : 0.f;
        w3 = (d3 == 0.f) ? 1.f : 0.f;
        w4 = (d4 == 0.f) ? 1.f : 0.f;
    } else {
        w0 = 1.f / d0; w1 = 1.f / d1; w2 = 1.f / d2_; w3 = 1.f / d3; w4 = 1.f / d4;
    }
    float wsum = w0 + w1 + w2 + w3 + w4;
    float lsum = w0 * labels[bi0] + w1 * labels[bi1] + w2 * labels[bi2]
               + w3 * labels[bi3] + w4 * labels[bi4];
    if (lane == 0) out[q] = lsum / wsum;
}

// ======================= fallback path (round-1, fp32) =====================
#define FB_QT     16
#define FB_NCHUNK 25
#define FB_NT     256

__global__ __launch_bounds__(FB_NT) void fb_phaseA(
        const float* __restrict__ x, const float* __restrict__ train,
        const float* __restrict__ x2, const float* __restrict__ t2,
        float* __restrict__ cand_d, int* __restrict__ cand_i,
        int N, int chunkSize) {
    __shared__ float xs[FB_QT][DIM + 4];
    __shared__ float rd[FB_QT][16 * KNN_K];
    __shared__ int   ri[FB_QT][16 * KNN_K];

    const int q0 = blockIdx.x * FB_QT;
    const int chunk = blockIdx.y;
    const int n0 = chunk * chunkSize;
    const int n1 = min(n0 + chunkSize, N);
    const int t = threadIdx.x;

    for (int i = t; i < FB_QT * DIM; i += FB_NT) {
        int q = i >> 7, d = i & (DIM - 1);
        xs[q][d] = x[(size_t)(q0 + q) * DIM + d];
    }
    __syncthreads();

    const int q  = t & (FB_QT - 1);
    const int ln = t >> 4;
    const float myx2 = x2[q0 + q];
    const float4* xp = (const float4*)xs[q];

    float bd0 = FLT_BIG, bd1 = FLT_BIG, bd2 = FLT_BIG, bd3 = FLT_BIG, bd4 = FLT_BIG;
    int   bi0 = -1, bi1 = -1, bi2 = -1, bi3 = -1, bi4 = -1;

    int n = n0 + ln;
    for (; n < n1; n += 16) {
        const float4* r0 = (const float4*)(train + (size_t)n * DIM);
        float dA = 0.f;
#pragma unroll 8
        for (int i = 0; i < DIM / 4; ++i) {
            float4 a = xp[i], b0 = r0[i];
            dA += a.x * b0.x + a.y * b0.y + a.z * b0.z + a.w * b0.w;
        }
        float vA = myx2 - 2.f * dA + t2[n];
        TOP5_INSERT(vA, n);
    }

    rd[q][ln * KNN_K + 0] = bd0;  ri[q][ln * KNN_K + 0] = bi0;
    rd[q][ln * KNN_K + 1] = bd1;  ri[q][ln * KNN_K + 1] = bi1;
    rd[q][ln * KNN_K + 2] = bd2;  ri[q][ln * KNN_K + 2] = bi2;
    rd[q][ln * KNN_K + 3] = bd3;  ri[q][ln * KNN_K + 3] = bi3;
    rd[q][ln * KNN_K + 4] = bd4;  ri[q][ln * KNN_K + 4] = bi4;
    __syncthreads();

    if (t < FB_QT) {
        float* dq = rd[t]; int* iq = ri[t];
        size_t base = ((size_t)(q0 + t) * FB_NCHUNK + chunk) * KNN_K;
#pragma unroll
        for (int k = 0; k < KNN_K; ++k) {
            float best = FLT_BIG; int bj = 0;
            for (int j = 0; j < 16 * KNN_K; ++j) {
                float v = dq[j];
                if (v < best) { best = v; bj = j; }
            }
            cand_d[base + k] = best; cand_i[base + k] = iq[bj];
            dq[bj] = FLT_BIG;
        }
    }
}

__global__ void fb_phaseB(const float* __restrict__ cand_d,
                          const int* __restrict__ cand_i,
                          const float* __restrict__ labels,
                          float* __restrict__ out, int B, int ncand) {
    int qq = blockIdx.x * blockDim.x + threadIdx.x;
    if (qq >= B) return;
    const float* cd = cand_d + (size_t)qq * ncand;
    const int*   ci = cand_i + (size_t)qq * ncand;

    float bd0 = FLT_BIG, bd1 = FLT_BIG, bd2 = FLT_BIG, bd3 = FLT_BIG, bd4 = FLT_BIG;
    int   bi0 = -1, bi1 = -1, bi2 = -1, bi3 = -1, bi4 = -1;
    for (int j = 0; j < ncand; ++j) {
        float v = cd[j]; int id = ci[j];
        TOP5_INSERT(v, id);
    }
    float d0 = sqrtf(fmaxf(bd0, 0.f));
    float d1 = sqrtf(fmaxf(bd1, 0.f));
    float d2 = sqrtf(fmaxf(bd2, 0.f));
    float d3 = sqrtf(fmaxf(bd3, 0.f));
    float d4 = sqrtf(fmaxf(bd4, 0.f));
    bool zero = (d0 == 0.f) || (d1 == 0.f) || (d2 == 0.f) || (d3 == 0.f) || (d4 == 0.f);
    float w0, w1, w2, w3, w4;
    if (zero) {
        w0 = (d0 == 0.f) ? 1.f : 0.f;
        w1 = (d1 == 0.f) ? 1.f : 0.f;
        w2 = (d2 == 0.f) ? 1.f : 0.f;
        w3 = (d3 == 0.f) ? 1.f : 0.f;
        w4 = (d4 == 0.f) ? 1.f : 0.f;
    } else {
        w0 = 1.f / d0; w1 = 1.f / d1; w2 = 1.f / d2; w3 = 1.f / d3; w4 = 1.f / d4;
    }
    float wsum = w0 + w1 + w2 + w3 + w4;
    float lsum = w0 * labels[bi0] + w1 * labels[bi1] + w2 * labels[bi2]
               + w3 * labels[bi3] + w4 * labels[bi4];
    out[qq] = lsum / wsum;
}

// ---------------------------------------------------------------- launch
static inline size_t align256(size_t v) { return (v + 255) & ~(size_t)255; }

extern "C" void kernel_launch(void* const* d_in, const int* in_sizes, int n_in,
                              void* d_out, int out_size, void* d_ws, size_t ws_size,
                              hipStream_t stream) {
    const float* x      = (const float*)d_in[0];   // [B, D] fp32
    const float* train  = (const float*)d_in[1];   // [N, D] fp32
    const float* labels = (const float*)d_in[2];   // [N]    fp32

    const int N = in_sizes[2];
    const int D = in_sizes[1] / N;
    const int B = in_sizes[0] / D;
    (void)n_in;

    // MFMA-path workspace layout
    size_t o_tbf  = 0;
    size_t o_xbf  = align256(o_tbf + (size_t)N * DIM * sizeof(ushortT));
    size_t o_t2   = align256(o_xbf + (size_t)B * DIM * sizeof(ushortT));
    size_t o_cd   = align256(o_t2 + (size_t)N * sizeof(float));
    size_t o_ci   = align256(o_cd + (size_t)B * MF_NCAND * sizeof(float));
    size_t need   = align256(o_ci + (size_t)B * MF_NCAND * sizeof(int));

    const bool mfma_ok = (N == MF_N) && (D == DIM) && (B == MF_B) && (ws_size >= need);

    if (mfma_ok) {
        ushortT* tbf = (ushortT*)((char*)d_ws + o_tbf);
        ushortT* xbf = (ushortT*)((char*)d_ws + o_xbf);
        float* t2    = (float*)((char*)d_ws + o_t2);
        float* cand_d = (float*)((char*)d_ws + o_cd);
        int*   cand_i = (int*)((char*)d_ws + o_ci);

        int ntrain = N * DIM, nx = B * DIM;
        cvt_bf16_kernel<<<ntrain / 1024, 256, 0, stream>>>(train, tbf, ntrain);
        cvt_bf16_kernel<<<nx / 1024, 256, 0, stream>>>(x, xbf, nx);
        rowsq_kernel<<<(N + 255) / 256, 256, 0, stream>>>(train, t2, N);

        dim3 gridA(MF_B / MF_QPB, MF_NCH);
        knn_mfma<<<gridA, 256, 0, stream>>>(xbf, tbf, t2, cand_d, cand_i);
        knn_final<<<MF_B, 64, 0, stream>>>(cand_d, cand_i, x, train, labels,
                                           (float*)d_out);
    } else {
        // round-1 fp32 fallback (correct, slower)
        float* t2     = (float*)d_ws;
        float* x2v    = t2 + N;
        float* cand_d = x2v + B;
        int*   cand_i = (int*)(cand_d + (size_t)B * FB_NCHUNK * KNN_K);

        rowsq_kernel<<<(N + 255) / 256, 256, 0, stream>>>(train, t2, N);
        rowsq_kernel<<<(B + 255) / 256, 256, 0, stream>>>(x, x2v, B);
        const int chunkSize = (N + FB_NCHUNK - 1) / FB_NCHUNK;
        dim3 gridA(B / FB_QT, FB_NCHUNK);
        fb_phaseA<<<gridA, FB_NT, 0, stream>>>(x, train, x2v, t2,
                                               cand_d, cand_i, N, chunkSize);
        fb_phaseB<<<(B + 255) / 256, 256, 0, stream>>>(cand_d, cand_i, labels,
                                                       (float*)d_out, B,
                                                       FB_NCHUNK * KNN_K);
    }
}

// Round 3
// 255.826 us; speedup vs baseline: 12.0493x; 1.2127x over previous
//
#include <hip/hip_runtime.h>
#include <math.h>

typedef __attribute__((ext_vector_type(8))) short bf16x8;
typedef __attribute__((ext_vector_type(4))) float f32x4;
typedef unsigned short ushortT;
typedef unsigned int uint32;

#define KNN_K   5
#define DIM     128
#define FLT_BIG 3.402823466e38f
#define KEY_C   512.0f          // shift so acc = -(key+C)/2 is always negative

// ---------------- MFMA-path constants (fixed problem shape) ----------------
#define MF_B     2048
#define MF_N     100000
#define MF_QPB   256              // queries per block (4 waves x 64)
#define MF_QPW   64
#define MF_NCH   250              // train chunks (2000 blocks -> 7.8/CU)
#define MF_CHS   400              // rows per chunk (250*400 = 100000)
#define MF_TILES (MF_CHS / 16)    // 25 MFMA row-tiles per chunk
#define MF_CSLOT 4                // candidates kept per (query, chunk)
#define MF_NCAND (MF_NCH * MF_CSLOT)   // 1000 per query

__device__ __forceinline__ uint32 umn(uint32 a, uint32 b) { return a < b ? a : b; }
__device__ __forceinline__ uint32 umx(uint32 a, uint32 b) { return a > b ? a : b; }

// Static-index top-5 insertion for exact fp32 phase-B merge.
#define TOP5_INSERT(v, id)                                                  \
    if ((v) < bd4) {                                                        \
        bool l0 = (v) < bd0, l1 = (v) < bd1, l2 = (v) < bd2, l3 = (v) < bd3;\
        if (l3) { bd4 = bd3; bi4 = bi3; } else { bd4 = (v); bi4 = (id); }   \
        if (l2) { bd3 = bd2; bi3 = bi2; } else if (l3) { bd3 = (v); bi3 = (id); } \
        if (l1) { bd2 = bd1; bi2 = bi1; } else if (l2) { bd2 = (v); bi2 = (id); } \
        if (l0) { bd1 = bd0; bi1 = bi0; } else if (l1) { bd1 = (v); bi1 = (id); } \
        if (l0) { bd0 = (v); bi0 = (id); }                                  \
    }

__device__ __forceinline__ ushortT f2bf(float f) {
    unsigned u = __float_as_uint(f);
    u += 0x7fffu + ((u >> 16) & 1u);   // RTNE
    return (ushortT)(u >> 16);
}

// ------------------------------------------------------------------- prep
// One wave per row: fp32 -> bf16 + fused norm key base t2c = -(|row|^2+C)/2.
__global__ void prep_kernel(const float* __restrict__ in,
                            ushortT* __restrict__ outbf,
                            float* __restrict__ t2c, int rows) {
    int row  = blockIdx.x * 4 + (threadIdx.x >> 6);
    int lane = threadIdx.x & 63;
    if (row >= rows) return;
    float2 v = *(const float2*)(in + (size_t)row * DIM + lane * 2);
    ushort2 o; o.x = f2bf(v.x); o.y = f2bf(v.y);
    *(ushort2*)(outbf + (size_t)row * DIM + lane * 2) = o;
    float s = v.x * v.x + v.y * v.y;
#pragma unroll
    for (int off = 32; off; off >>= 1) s += __shfl_xor(s, off);
    if (lane == 0) t2c[row] = -(s + KEY_C) * 0.5f;
}

// ---------------------------------------------------------------- phase A
// grid = (MF_B/MF_QPB, MF_NCH), block = 256 (4 waves).
// acc init = -(t2+C)/2, so acc_final = -(key+C)/2 < 0 always; for negative
// floats, unsigned-bit order is reversed -> min_u32 on bits == min on key.
// Packed candidate = (acc_bits & ~1023) | chunk_local_row  (row < 400).
// Branch-free sorted-3 kept list per (lane, qtile) via min/max networks.
__global__ __launch_bounds__(256) void knn_mfma(
        const ushortT* __restrict__ xbf, const ushortT* __restrict__ tbf,
        const float* __restrict__ t2c,
        uint32* __restrict__ cand_k, uint32* __restrict__ cand_i) {
    __shared__ uint32 sk[4][MF_QPW][12];

    const int tid  = threadIdx.x;
    const int wv   = tid >> 6;
    const int lane = tid & 63;
    const int quad = lane >> 4;
    const int c16  = lane & 15;
    const int qbase = blockIdx.x * MF_QPB + wv * MF_QPW;
    const int n0 = blockIdx.y * MF_CHS;

    // B-fragments: 64 queries x K=128 in registers. bq[qtile][kstep]
    bf16x8 bq[4][4];
#pragma unroll
    for (int t = 0; t < 4; ++t)
#pragma unroll
        for (int s = 0; s < 4; ++s)
            bq[t][s] = *(const bf16x8*)(xbf + (size_t)(qbase + t * 16 + c16) * DIM
                                        + s * 32 + quad * 8);

    uint32 L[4][3];
#pragma unroll
    for (int t = 0; t < 4; ++t) { L[t][0] = 0xFFFFFFFFu; L[t][1] = 0xFFFFFFFFu; L[t][2] = 0xFFFFFFFFu; }

    const ushortT* ap = tbf + (size_t)(n0 + c16) * DIM + quad * 8;
    const float*   tp = t2c + n0 + quad * 4;

    bf16x8 fa[4];
#pragma unroll
    for (int s = 0; s < 4; ++s) fa[s] = *(const bf16x8*)(ap + s * 32);
    float4 tv = *(const float4*)tp;

    int locb = quad * 4;                    // chunk-local row of acc reg 0
    for (int tile = 0; tile < MF_TILES; ++tile) {
        const int nx = (tile + 1 < MF_TILES) ? tile + 1 : 0;
        const ushortT* np = ap + (size_t)nx * (16 * DIM);
        bf16x8 fb[4];
#pragma unroll
        for (int s = 0; s < 4; ++s) fb[s] = *(const bf16x8*)(np + s * 32);
        float4 tn = *(const float4*)(tp + nx * 16);

        f32x4 acc[4];
#pragma unroll
        for (int t = 0; t < 4; ++t) acc[t] = (f32x4){tv.x, tv.y, tv.z, tv.w};
#pragma unroll
        for (int s = 0; s < 4; ++s)
#pragma unroll
            for (int t = 0; t < 4; ++t)
                acc[t] = __builtin_amdgcn_mfma_f32_16x16x32_bf16(
                             fa[s], bq[t][s], acc[t], 0, 0, 0);

#pragma unroll
        for (int t = 0; t < 4; ++t) {
            uint32 p0 = (__float_as_uint(acc[t][0]) & 0xFFFFFC00u) | (uint32)(locb + 0);
            uint32 p1 = (__float_as_uint(acc[t][1]) & 0xFFFFFC00u) | (uint32)(locb + 1);
            uint32 p2 = (__float_as_uint(acc[t][2]) & 0xFFFFFC00u) | (uint32)(locb + 2);
            uint32 p3 = (__float_as_uint(acc[t][3]) & 0xFFFFFC00u) | (uint32)(locb + 3);
            // sorted lowest-3 of 4
            uint32 m0 = umn(p0, p1), M0 = umx(p0, p1);
            uint32 m1 = umn(p2, p3), M1 = umx(p2, p3);
            uint32 s0 = umn(m0, m1);
            uint32 c  = umx(m0, m1), d = umn(M0, M1);
            uint32 s1 = umn(c, d),   s2 = umx(c, d);
            // merge sorted-3 (kept) with sorted-3 (new) -> sorted lowest-3
            uint32 a0 = L[t][0], a1 = L[t][1], a2 = L[t][2];
            uint32 cc = umx(a0, s0), dd = umn(a1, s1);
            uint32 ee = umx(a1, s1), ff = umn(a2, s2);
            L[t][0] = umn(a0, s0);
            L[t][1] = umn(cc, dd);
            L[t][2] = umn(umx(cc, dd), umn(ee, ff));
        }
        locb += 16;
#pragma unroll
        for (int s = 0; s < 4; ++s) fa[s] = fb[s];
        tv = tn;
    }

    // 4 quads x sorted-3 = 12 candidates per query
#pragma unroll
    for (int t = 0; t < 4; ++t)
#pragma unroll
        for (int j = 0; j < 3; ++j)
            sk[wv][t * 16 + c16][quad * 3 + j] = L[t][j];
    __syncthreads();

    // thread m owns block-query m: flat top-4 of 12 (branch-free network)
    const int mw = tid >> 6, ml = tid & 63;
    uint32 k0 = 0xFFFFFFFFu, k1 = 0xFFFFFFFFu, k2 = 0xFFFFFFFFu, k3 = 0xFFFFFFFFu;
#pragma unroll
    for (int j = 0; j < 12; ++j) {
        uint32 v = sk[mw][ml][j];
        uint32 t0 = umx(k0, v);
        k0 = umn(k0, v);
        uint32 t1 = umx(k1, t0);
        k1 = umn(k1, t0);
        uint32 t2_ = umx(k2, t1);
        k2 = umn(k2, t1);
        k3 = umn(k3, t2_);
    }
    const size_t base = ((size_t)(blockIdx.x * MF_QPB + tid) * MF_NCH + blockIdx.y)
                        * MF_CSLOT;
    uint4 kk; kk.x = k0; kk.y = k1; kk.z = k2; kk.w = k3;
    uint4 ii; ii.x = n0 + (k0 & 1023u); ii.y = n0 + (k1 & 1023u);
    ii.z = n0 + (k2 & 1023u); ii.w = n0 + (k3 & 1023u);
    *(uint4*)(cand_k + base) = kk;
    *(uint4*)(cand_i + base) = ii;
}

// ---------------------------------------------------------------- phase B
// One wave per query: top-16 of 1000 u32-keyed candidates via threshold
// scan, exact fp32 rescore, exact top-5, inverse-distance weighted average.
__global__ __launch_bounds__(64) void knn_final(
        const uint32* __restrict__ cand_k, const uint32* __restrict__ cand_i,
        const float* __restrict__ x, const float* __restrict__ train,
        const float* __restrict__ labels, float* __restrict__ out) {
    const int q = blockIdx.x;
    const int lane = threadIdx.x;
    const float xa = x[(size_t)q * DIM + lane];
    const float xb = x[(size_t)q * DIM + 64 + lane];

    uint32 ck[16]; uint32 cid[16];
    const size_t cb = (size_t)q * MF_NCAND;
#pragma unroll
    for (int j = 0; j < 16; ++j) {
        int p = lane + 64 * j;
        if (p < MF_NCAND) { ck[j] = cand_k[cb + p]; cid[j] = cand_i[cb + p]; }
        else { ck[j] = 0xFFFFFFFFu; cid[j] = 0x7FFFFFFFu; }
    }

    float bd0 = FLT_BIG, bd1 = FLT_BIG, bd2 = FLT_BIG, bd3 = FLT_BIG, bd4 = FLT_BIG;
    int   bi0 = 0, bi1 = 0, bi2 = 0, bi3 = 0, bi4 = 0;
    uint32 tk = 0; uint32 ti = 0;  bool first = true;

    for (int round = 0; round < 16; ++round) {
        uint32 mk = 0xFFFFFFFFu, mi = 0xFFFFFFFFu;
#pragma unroll
        for (int j = 0; j < 16; ++j) {
            bool gt = first || (ck[j] > tk) || (ck[j] == tk && cid[j] > ti);
            if (gt && ((ck[j] < mk) || (ck[j] == mk && cid[j] < mi))) {
                mk = ck[j]; mi = cid[j];
            }
        }
#pragma unroll
        for (int off = 32; off; off >>= 1) {
            uint32 ok = __shfl_xor(mk, off);
            uint32 oi = __shfl_xor(mi, off);
            if (ok < mk || (ok == mk && oi < mi)) { mk = ok; mi = oi; }
        }
        tk = mk; ti = mi; first = false;
        // exact fp32 rescore
        const float* tr = train + (size_t)mi * DIM;
        float da = xa - tr[lane];
        float db = xb - tr[64 + lane];
        float d2 = fmaf(da, da, db * db);
#pragma unroll
        for (int off = 32; off; off >>= 1) d2 += __shfl_xor(d2, off);
        TOP5_INSERT(d2, (int)mi);
    }

    float d0 = sqrtf(fmaxf(bd0, 0.f));
    float d1 = sqrtf(fmaxf(bd1, 0.f));
    float d2_ = sqrtf(fmaxf(bd2, 0.f));
    float d3 = sqrtf(fmaxf(bd3, 0.f));
    float d4 = sqrtf(fmaxf(bd4, 0.f));
    bool zero = (d0 == 0.f) || (d1 == 0.f) || (d2_ == 0.f) || (d3 == 0.f) || (d4 == 0.f);
    float w0, w1, w2, w3, w4;
    if (zero) {
        w0 = (d0 == 0.f) ? 1.f : 0.f;
        w1 = (d1 == 0.f) ? 1.f : 0.f;
        w2 = (d2_ == 0.f) ? 1.f : 0.f;
        w3 = (d3 == 0.f) ? 1.f : 0.f;
        w4 = (d4 == 0.f) ? 1.f : 0.f;
    } else {
        w0 = 1.f / d0; w1 = 1.f / d1; w2 = 1.f / d2_; w3 = 1.f / d3; w4 = 1.f / d4;
    }
    float wsum = w0 + w1 + w2 + w3 + w4;
    float lsum = w0 * labels[bi0] + w1 * labels[bi1] + w2 * labels[bi2]
               + w3 * labels[bi3] + w4 * labels[bi4];
    if (lane == 0) out[q] = lsum / wsum;
}

// ======================= fallback path (round-1, fp32) =====================
#define FB_QT     16
#define FB_NCHUNK 25
#define FB_NT     256

__global__ void rowsq_kernel(const float* __restrict__ data,
                             float* __restrict__ out, int rows) {
    int r = blockIdx.x * blockDim.x + threadIdx.x;
    if (r >= rows) return;
    const float4* p = (const float4*)(data + (size_t)r * DIM);
    float s0 = 0.f, s1 = 0.f, s2 = 0.f, s3 = 0.f;
#pragma unroll
    for (int i = 0; i < DIM / 4; ++i) {
        float4 v = p[i];
        s0 += v.x * v.x; s1 += v.y * v.y; s2 += v.z * v.z; s3 += v.w * v.w;
    }
    out[r] = (s0 + s1) + (s2 + s3);
}

__global__ __launch_bounds__(FB_NT) void fb_phaseA(
        const float* __restrict__ x, const float* __restrict__ train,
        const float* __restrict__ x2, const float* __restrict__ t2,
        float* __restrict__ cand_d, int* __restrict__ cand_i,
        int N, int chunkSize) {
    __shared__ float xs[FB_QT][DIM + 4];
    __shared__ float rd[FB_QT][16 * KNN_K];
    __shared__ int   ri[FB_QT][16 * KNN_K];

    const int q0 = blockIdx.x * FB_QT;
    const int chunk = blockIdx.y;
    const int n0 = chunk * chunkSize;
    const int n1 = min(n0 + chunkSize, N);
    const int t = threadIdx.x;

    for (int i = t; i < FB_QT * DIM; i += FB_NT) {
        int q = i >> 7, d = i & (DIM - 1);
        xs[q][d] = x[(size_t)(q0 + q) * DIM + d];
    }
    __syncthreads();

    const int q  = t & (FB_QT - 1);
    const int ln = t >> 4;
    const float myx2 = x2[q0 + q];
    const float4* xp = (const float4*)xs[q];

    float bd0 = FLT_BIG, bd1 = FLT_BIG, bd2 = FLT_BIG, bd3 = FLT_BIG, bd4 = FLT_BIG;
    int   bi0 = -1, bi1 = -1, bi2 = -1, bi3 = -1, bi4 = -1;

    int n = n0 + ln;
    for (; n < n1; n += 16) {
        const float4* r0 = (const float4*)(train + (size_t)n * DIM);
        float dA = 0.f;
#pragma unroll 8
        for (int i = 0; i < DIM / 4; ++i) {
            float4 a = xp[i], b0 = r0[i];
            dA += a.x * b0.x + a.y * b0.y + a.z * b0.z + a.w * b0.w;
        }
        float vA = myx2 - 2.f * dA + t2[n];
        TOP5_INSERT(vA, n);
    }

    rd[q][ln * KNN_K + 0] = bd0;  ri[q][ln * KNN_K + 0] = bi0;
    rd[q][ln * KNN_K + 1] = bd1;  ri[q][ln * KNN_K + 1] = bi1;
    rd[q][ln * KNN_K + 2] = bd2;  ri[q][ln * KNN_K + 2] = bi2;
    rd[q][ln * KNN_K + 3] = bd3;  ri[q][ln * KNN_K + 3] = bi3;
    rd[q][ln * KNN_K + 4] = bd4;  ri[q][ln * KNN_K + 4] = bi4;
    __syncthreads();

    if (t < FB_QT) {
        float* dq = rd[t]; int* iq = ri[t];
        size_t base = ((size_t)(q0 + t) * FB_NCHUNK + chunk) * KNN_K;
#pragma unroll
        for (int k = 0; k < KNN_K; ++k) {
            float best = FLT_BIG; int bj = 0;
            for (int j = 0; j < 16 * KNN_K; ++j) {
                float v = dq[j];
                if (v < best) { best = v; bj = j; }
            }
            cand_d[base + k] = best; cand_i[base + k] = iq[bj];
            dq[bj] = FLT_BIG;
        }
    }
}

__global__ void fb_phaseB(const float* __restrict__ cand_d,
                          const int* __restrict__ cand_i,
                          const float* __restrict__ labels,
                          float* __restrict__ out, int B, int ncand) {
    int qq = blockIdx.x * blockDim.x + threadIdx.x;
    if (qq >= B) return;
    const float* cd = cand_d + (size_t)qq * ncand;
    const int*   ci = cand_i + (size_t)qq * ncand;

    float bd0 = FLT_BIG, bd1 = FLT_BIG, bd2 = FLT_BIG, bd3 = FLT_BIG, bd4 = FLT_BIG;
    int   bi0 = -1, bi1 = -1, bi2 = -1, bi3 = -1, bi4 = -1;
    for (int j = 0; j < ncand; ++j) {
        float v = cd[j]; int id = ci[j];
        TOP5_INSERT(v, id);
    }
    float d0 = sqrtf(fmaxf(bd0, 0.f));
    float d1 = sqrtf(fmaxf(bd1, 0.f));
    float d2 = sqrtf(fmaxf(bd2, 0.f));
    float d3 = sqrtf(fmaxf(bd3, 0.f));
    float d4 = sqrtf(fmaxf(bd4, 0.f));
    bool zero = (d0 == 0.f) || (d1 == 0.f) || (d2 == 0.f) || (d3 == 0.f) || (d4 == 0.f);
    float w0, w1, w2, w3, w4;
    if (zero) {
        w0 = (d0 == 0.f) ? 1.f : 0.f;
        w1 = (d1 == 0.f) ? 1.f : 0.f;
        w2 = (d2 == 0.f) ? 1.f : 0.f;
        w3 = (d3 == 0.f) ? 1.f : 0.f;
        w4 = (d4 == 0.f) ? 1.f : 0.f;
    } else {
        w0 = 1.f / d0; w1 = 1.f / d1; w2 = 1.f / d2; w3 = 1.f / d3; w4 = 1.f / d4;
    }
    float wsum = w0 + w1 + w2 + w3 + w4;
    float lsum = w0 * labels[bi0] + w1 * labels[bi1] + w2 * labels[bi2]
               + w3 * labels[bi3] + w4 * labels[bi4];
    out[qq] = lsum / wsum;
}

// ---------------------------------------------------------------- launch
static inline size_t align256(size_t v) { return (v + 255) & ~(size_t)255; }

extern "C" void kernel_launch(void* const* d_in, const int* in_sizes, int n_in,
                              void* d_out, int out_size, void* d_ws, size_t ws_size,
                              hipStream_t stream) {
    const float* x      = (const float*)d_in[0];   // [B, D] fp32
    const float* train  = (const float*)d_in[1];   // [N, D] fp32
    const float* labels = (const float*)d_in[2];   // [N]    fp32

    const int N = in_sizes[2];
    const int D = in_sizes[1] / N;
    const int B = in_sizes[0] / D;
    (void)n_in;

    size_t o_tbf = 0;
    size_t o_xbf = align256(o_tbf + (size_t)N * DIM * sizeof(ushortT));
    size_t o_t2c = align256(o_xbf + (size_t)B * DIM * sizeof(ushortT));
    size_t o_x2d = align256(o_t2c + (size_t)N * sizeof(float));   // dummy x-norms
    size_t o_ck  = align256(o_x2d + (size_t)B * sizeof(float));
    size_t o_ci  = align256(o_ck + (size_t)B * MF_NCAND * sizeof(uint32));
    size_t need  = align256(o_ci + (size_t)B * MF_NCAND * sizeof(uint32));

    const bool mfma_ok = (N == MF_N) && (D == DIM) && (B == MF_B) && (ws_size >= need);

    if (mfma_ok) {
        ushortT* tbf = (ushortT*)((char*)d_ws + o_tbf);
        ushortT* xbf = (ushortT*)((char*)d_ws + o_xbf);
        float* t2c   = (float*)((char*)d_ws + o_t2c);
        float* x2d   = (float*)((char*)d_ws + o_x2d);
        uint32* cand_k = (uint32*)((char*)d_ws + o_ck);
        uint32* cand_i = (uint32*)((char*)d_ws + o_ci);

        prep_kernel<<<(N + 3) / 4, 256, 0, stream>>>(train, tbf, t2c, N);
        prep_kernel<<<(B + 3) / 4, 256, 0, stream>>>(x, xbf, x2d, B);

        dim3 gridA(MF_B / MF_QPB, MF_NCH);
        knn_mfma<<<gridA, 256, 0, stream>>>(xbf, tbf, t2c, cand_k, cand_i);
        knn_final<<<MF_B, 64, 0, stream>>>(cand_k, cand_i, x, train, labels,
                                           (float*)d_out);
    } else {
        float* t2     = (float*)d_ws;
        float* x2v    = t2 + N;
        float* cand_d = x2v + B;
        int*   cand_i = (int*)(cand_d + (size_t)B * FB_NCHUNK * KNN_K);

        rowsq_kernel<<<(N + 255) / 256, 256, 0, stream>>>(train, t2, N);
        rowsq_kernel<<<(B + 255) / 256, 256, 0, stream>>>(x, x2v, B);
        const int chunkSize = (N + FB_NCHUNK - 1) / FB_NCHUNK;
        dim3 gridA(B / FB_QT, FB_NCHUNK);
        fb_phaseA<<<gridA, FB_NT, 0, stream>>>(x, train, x2v, t2,
                                               cand_d, cand_i, N, chunkSize);
        fb_phaseB<<<(B + 255) / 256, 256, 0, stream>>>(cand_d, cand_i, labels,
                                                       (float*)d_out, B,
                                                       FB_NCHUNK * KNN_K);
    }
}

// Round 4
// 237.111 us; speedup vs baseline: 13.0003x; 1.0789x over previous
//
#include <hip/hip_runtime.h>
#include <math.h>

typedef __attribute__((ext_vector_type(8))) short bf16x8;
typedef __attribute__((ext_vector_type(4))) float f32x4;
typedef unsigned short ushortT;
typedef unsigned int uint32;

#define KNN_K   5
#define DIM     128
#define FLT_BIG 3.402823466e38f
#define KEY_C   512.0f          // shift so acc = -(key+C)/2 is always negative

// ---------------- MFMA-path constants (fixed problem shape) ----------------
#define MF_B     2048
#define MF_N     100000
#define MF_QPB   256              // queries per block (4 waves x 64)
#define MF_QPW   64
#define MF_NCH   250              // train chunks
#define MF_CHS   400              // rows per chunk (250*400 = 100000)
#define MF_TILES (MF_CHS / 16)    // 25 MFMA row-tiles per chunk
#define MF_CSLOT 4                // candidates kept per (query, chunk)
#define MF_NCAND (MF_NCH * MF_CSLOT)   // 1000 per query
#define MF_RESCORE 10             // phase-B exact-rescore depth

__device__ __forceinline__ uint32 umn(uint32 a, uint32 b) { return a < b ? a : b; }
__device__ __forceinline__ uint32 umx(uint32 a, uint32 b) { return a > b ? a : b; }

// Static-index top-5 insertion for exact fp32 phase-B merge.
#define TOP5_INSERT(v, id)                                                  \
    if ((v) < bd4) {                                                        \
        bool l0 = (v) < bd0, l1 = (v) < bd1, l2 = (v) < bd2, l3 = (v) < bd3;\
        if (l3) { bd4 = bd3; bi4 = bi3; } else { bd4 = (v); bi4 = (id); }   \
        if (l2) { bd3 = bd2; bi3 = bi2; } else if (l3) { bd3 = (v); bi3 = (id); } \
        if (l1) { bd2 = bd1; bi2 = bi1; } else if (l2) { bd2 = (v); bi2 = (id); } \
        if (l0) { bd1 = bd0; bi1 = bi0; } else if (l1) { bd1 = (v); bi1 = (id); } \
        if (l0) { bd0 = (v); bi0 = (id); }                                  \
    }

__device__ __forceinline__ uint32 f2bf_u(float f) {
    unsigned u = __float_as_uint(f);
    u += 0x7fffu + ((u >> 16) & 1u);   // RTNE
    return u >> 16;
}

// ------------------------------------------------------------------- prep
// 16 rows per wave, 64 rows per block. Lane handles 32 contiguous floats of
// one row: 8 float4 loads, 4 uint4 bf16 stores, 2-shfl quad reduction for
// the norm key base t2c = -(|row|^2 + C)/2.
__global__ __launch_bounds__(256) void prep_kernel(const float* __restrict__ in,
                                                   ushortT* __restrict__ outbf,
                                                   float* __restrict__ t2c, int rows) {
    const int wv = threadIdx.x >> 6, lane = threadIdx.x & 63;
    const int row = (blockIdx.x * 4 + wv) * 16 + (lane >> 2);
    if (row >= rows) return;
    const int seg = (lane & 3) * 32;                  // 32 floats per lane
    const float4* p = (const float4*)(in + (size_t)row * DIM + seg);

    float4 v[8];
#pragma unroll
    for (int j = 0; j < 8; ++j) v[j] = p[j];

    uint32 u[16];
#pragma unroll
    for (int j = 0; j < 8; ++j) {
        u[2 * j]     = f2bf_u(v[j].x) | (f2bf_u(v[j].y) << 16);
        u[2 * j + 1] = f2bf_u(v[j].z) | (f2bf_u(v[j].w) << 16);
    }
    uint4* o = (uint4*)(outbf + (size_t)row * DIM + seg);
#pragma unroll
    for (int j = 0; j < 4; ++j)
        o[j] = make_uint4(u[4 * j], u[4 * j + 1], u[4 * j + 2], u[4 * j + 3]);

    float s = 0.f;
#pragma unroll
    for (int j = 0; j < 8; ++j)
        s += v[j].x * v[j].x + v[j].y * v[j].y + v[j].z * v[j].z + v[j].w * v[j].w;
    s += __shfl_xor(s, 1);
    s += __shfl_xor(s, 2);
    if ((lane & 3) == 0) t2c[row] = -(s + KEY_C) * 0.5f;
}

// ---------------------------------------------------------------- phase A
// grid = (MF_NCH, MF_B/MF_QPB)  [chunk-major dispatch: same-chunk blocks get
// adjacent flat IDs only 250 apart -> partial XCD co-location for L2 reuse].
// acc init = -(t2+C)/2, so acc_final = -(key+C)/2 < 0 always; negative
// floats order reversed as u32 -> min_u32 on bits == min on key.
// Packed candidate = (acc_bits & ~1023) | chunk_local_row.
__global__ __launch_bounds__(256) void knn_mfma(
        const ushortT* __restrict__ xbf, const ushortT* __restrict__ tbf,
        const float* __restrict__ t2c,
        uint32* __restrict__ cand_k, uint32* __restrict__ cand_i) {
    __shared__ uint32 sk[4][MF_QPW][12];

    const int tid  = threadIdx.x;
    const int wv   = tid >> 6;
    const int lane = tid & 63;
    const int quad = lane >> 4;
    const int c16  = lane & 15;
    const int chunk = blockIdx.x;
    const int qbase = blockIdx.y * MF_QPB + wv * MF_QPW;
    const int n0 = chunk * MF_CHS;

    // B-fragments: 64 queries x K=128 in registers. bq[qtile][kstep]
    bf16x8 bq[4][4];
#pragma unroll
    for (int t = 0; t < 4; ++t)
#pragma unroll
        for (int s = 0; s < 4; ++s)
            bq[t][s] = *(const bf16x8*)(xbf + (size_t)(qbase + t * 16 + c16) * DIM
                                        + s * 32 + quad * 8);

    uint32 L[4][3];
#pragma unroll
    for (int t = 0; t < 4; ++t) { L[t][0] = 0xFFFFFFFFu; L[t][1] = 0xFFFFFFFFu; L[t][2] = 0xFFFFFFFFu; }

    const ushortT* ap = tbf + (size_t)(n0 + c16) * DIM + quad * 8;
    const float*   tp = t2c + n0 + quad * 4;

    bf16x8 fa[4];
#pragma unroll
    for (int s = 0; s < 4; ++s) fa[s] = *(const bf16x8*)(ap + s * 32);
    float4 tv = *(const float4*)tp;

    int locb = quad * 4;                    // chunk-local row of acc reg 0
    for (int tile = 0; tile < MF_TILES; ++tile) {
        const int nx = (tile + 1 < MF_TILES) ? tile + 1 : 0;
        const ushortT* np = ap + (size_t)nx * (16 * DIM);
        bf16x8 fb[4];
#pragma unroll
        for (int s = 0; s < 4; ++s) fb[s] = *(const bf16x8*)(np + s * 32);
        float4 tn = *(const float4*)(tp + nx * 16);

        f32x4 acc[4];
#pragma unroll
        for (int t = 0; t < 4; ++t) acc[t] = (f32x4){tv.x, tv.y, tv.z, tv.w};
#pragma unroll
        for (int s = 0; s < 4; ++s)
#pragma unroll
            for (int t = 0; t < 4; ++t)
                acc[t] = __builtin_amdgcn_mfma_f32_16x16x32_bf16(
                             fa[s], bq[t][s], acc[t], 0, 0, 0);

#pragma unroll
        for (int t = 0; t < 4; ++t) {
            uint32 p0 = (__float_as_uint(acc[t][0]) & 0xFFFFFC00u) | (uint32)(locb + 0);
            uint32 p1 = (__float_as_uint(acc[t][1]) & 0xFFFFFC00u) | (uint32)(locb + 1);
            uint32 p2 = (__float_as_uint(acc[t][2]) & 0xFFFFFC00u) | (uint32)(locb + 2);
            uint32 p3 = (__float_as_uint(acc[t][3]) & 0xFFFFFC00u) | (uint32)(locb + 3);
            // sorted lowest-3 of 4
            uint32 m0 = umn(p0, p1), M0 = umx(p0, p1);
            uint32 m1 = umn(p2, p3), M1 = umx(p2, p3);
            uint32 s0 = umn(m0, m1);
            uint32 c  = umx(m0, m1), d = umn(M0, M1);
            uint32 s1 = umn(c, d),   s2 = umx(c, d);
            // merge sorted-3 (kept) with sorted-3 (new)
            uint32 a0 = L[t][0], a1 = L[t][1], a2 = L[t][2];
            uint32 cc = umx(a0, s0), dd = umn(a1, s1);
            uint32 ee = umx(a1, s1), ff = umn(a2, s2);
            L[t][0] = umn(a0, s0);
            L[t][1] = umn(cc, dd);
            L[t][2] = umn(umx(cc, dd), umn(ee, ff));
        }
        locb += 16;
#pragma unroll
        for (int s = 0; s < 4; ++s) fa[s] = fb[s];
        tv = tn;
    }

    // 4 quads x sorted-3 = 12 candidates per query
#pragma unroll
    for (int t = 0; t < 4; ++t)
#pragma unroll
        for (int j = 0; j < 3; ++j)
            sk[wv][t * 16 + c16][quad * 3 + j] = L[t][j];
    __syncthreads();

    // thread m owns block-query m: flat top-4 of 12 (branch-free network)
    const int mw = tid >> 6, ml = tid & 63;
    uint32 k0 = 0xFFFFFFFFu, k1 = 0xFFFFFFFFu, k2 = 0xFFFFFFFFu, k3 = 0xFFFFFFFFu;
#pragma unroll
    for (int j = 0; j < 12; ++j) {
        uint32 v = sk[mw][ml][j];
        uint32 t0 = umx(k0, v);
        k0 = umn(k0, v);
        uint32 t1 = umx(k1, t0);
        k1 = umn(k1, t0);
        uint32 t2_ = umx(k2, t1);
        k2 = umn(k2, t1);
        k3 = umn(k3, t2_);
    }
    const size_t base = ((size_t)(blockIdx.y * MF_QPB + tid) * MF_NCH + chunk)
                        * MF_CSLOT;
    uint4 kk; kk.x = k0; kk.y = k1; kk.z = k2; kk.w = k3;
    uint4 ii; ii.x = n0 + (k0 & 1023u); ii.y = n0 + (k1 & 1023u);
    ii.z = n0 + (k2 & 1023u); ii.w = n0 + (k3 & 1023u);
    *(uint4*)(cand_k + base) = kk;
    *(uint4*)(cand_i + base) = ii;
}

// ---------------------------------------------------------------- phase B
// One wave per query. Stage 1: MF_RESCORE pure-VALU selection rounds over the
// 1000 u32-keyed candidates (no loads in the dependence chain). Stage 2: all
// rescore row-loads issued in parallel (one latency, not serialized), exact
// fp32 d2, exact top-5, inverse-distance weighted average.
__global__ __launch_bounds__(64) void knn_final(
        const uint32* __restrict__ cand_k, const uint32* __restrict__ cand_i,
        const float* __restrict__ x, const float* __restrict__ train,
        const float* __restrict__ labels, float* __restrict__ out) {
    const int q = blockIdx.x;
    const int lane = threadIdx.x;
    const float xa = x[(size_t)q * DIM + lane];
    const float xb = x[(size_t)q * DIM + 64 + lane];

    uint32 ck[16]; uint32 cid[16];
    const size_t cb = (size_t)q * MF_NCAND;
#pragma unroll
    for (int j = 0; j < 16; ++j) {
        int p = lane + 64 * j;
        if (p < MF_NCAND) { ck[j] = cand_k[cb + p]; cid[j] = cand_i[cb + p]; }
        else { ck[j] = 0xFFFFFFFFu; cid[j] = 0x7FFFFFFFu; }
    }

    // stage 1: select MF_RESCORE smallest (ck, cid) lexicographic, ids only
    uint32 selid[MF_RESCORE];
    uint32 tk = 0, ti = 0; bool first = true;
#pragma unroll
    for (int round = 0; round < MF_RESCORE; ++round) {
        uint32 mk = 0xFFFFFFFFu, mi = 0xFFFFFFFFu;
#pragma unroll
        for (int j = 0; j < 16; ++j) {
            bool gt = first || (ck[j] > tk) || (ck[j] == tk && cid[j] > ti);
            if (gt && ((ck[j] < mk) || (ck[j] == mk && cid[j] < mi))) {
                mk = ck[j]; mi = cid[j];
            }
        }
#pragma unroll
        for (int off = 32; off; off >>= 1) {
            uint32 ok = __shfl_xor(mk, off);
            uint32 oi = __shfl_xor(mi, off);
            if (ok < mk || (ok == mk && oi < mi)) { mk = ok; mi = oi; }
        }
        selid[round] = mi;
        tk = mk; ti = mi; first = false;
    }

    // stage 2: parallel exact fp32 rescore of all selected rows
    float d2v[MF_RESCORE];
#pragma unroll
    for (int r = 0; r < MF_RESCORE; ++r) {
        const float* tr = train + (size_t)selid[r] * DIM;
        float da = xa - tr[lane];
        float db = xb - tr[64 + lane];
        d2v[r] = fmaf(da, da, db * db);
    }
#pragma unroll
    for (int r = 0; r < MF_RESCORE; ++r) {
#pragma unroll
        for (int off = 32; off; off >>= 1) d2v[r] += __shfl_xor(d2v[r], off);
    }

    float bd0 = FLT_BIG, bd1 = FLT_BIG, bd2 = FLT_BIG, bd3 = FLT_BIG, bd4 = FLT_BIG;
    int   bi0 = 0, bi1 = 0, bi2 = 0, bi3 = 0, bi4 = 0;
#pragma unroll
    for (int r = 0; r < MF_RESCORE; ++r) {
        float v = d2v[r]; int id = (int)selid[r];
        TOP5_INSERT(v, id);
    }

    float d0 = sqrtf(fmaxf(bd0, 0.f));
    float d1 = sqrtf(fmaxf(bd1, 0.f));
    float d2_ = sqrtf(fmaxf(bd2, 0.f));
    float d3 = sqrtf(fmaxf(bd3, 0.f));
    float d4 = sqrtf(fmaxf(bd4, 0.f));
    bool zero = (d0 == 0.f) || (d1 == 0.f) || (d2_ == 0.f) || (d3 == 0.f) || (d4 == 0.f);
    float w0, w1, w2, w3, w4;
    if (zero) {
        w0 = (d0 == 0.f) ? 1.f : 0.f;
        w1 = (d1 == 0.f) ? 1.f : 0.f;
        w2 = (d2_ == 0.f) ? 1.f : 0.f;
        w3 = (d3 == 0.f) ? 1.f : 0.f;
        w4 = (d4 == 0.f) ? 1.f : 0.f;
    } else {
        w0 = 1.f / d0; w1 = 1.f / d1; w2 = 1.f / d2_; w3 = 1.f / d3; w4 = 1.f / d4;
    }
    float wsum = w0 + w1 + w2 + w3 + w4;
    float lsum = w0 * labels[bi0] + w1 * labels[bi1] + w2 * labels[bi2]
               + w3 * labels[bi3] + w4 * labels[bi4];
    if (lane == 0) out[q] = lsum / wsum;
}

// ======================= fallback path (round-1, fp32) =====================
#define FB_QT     16
#define FB_NCHUNK 25
#define FB_NT     256

__global__ void rowsq_kernel(const float* __restrict__ data,
                             float* __restrict__ out, int rows) {
    int r = blockIdx.x * blockDim.x + threadIdx.x;
    if (r >= rows) return;
    const float4* p = (const float4*)(data + (size_t)r * DIM);
    float s0 = 0.f, s1 = 0.f, s2 = 0.f, s3 = 0.f;
#pragma unroll
    for (int i = 0; i < DIM / 4; ++i) {
        float4 v = p[i];
        s0 += v.x * v.x; s1 += v.y * v.y; s2 += v.z * v.z; s3 += v.w * v.w;
    }
    out[r] = (s0 + s1) + (s2 + s3);
}

__global__ __launch_bounds__(FB_NT) void fb_phaseA(
        const float* __restrict__ x, const float* __restrict__ train,
        const float* __restrict__ x2, const float* __restrict__ t2,
        float* __restrict__ cand_d, int* __restrict__ cand_i,
        int N, int chunkSize) {
    __shared__ float xs[FB_QT][DIM + 4];
    __shared__ float rd[FB_QT][16 * KNN_K];
    __shared__ int   ri[FB_QT][16 * KNN_K];

    const int q0 = blockIdx.x * FB_QT;
    const int chunk = blockIdx.y;
    const int n0 = chunk * chunkSize;
    const int n1 = min(n0 + chunkSize, N);
    const int t = threadIdx.x;

    for (int i = t; i < FB_QT * DIM; i += FB_NT) {
        int q = i >> 7, d = i & (DIM - 1);
        xs[q][d] = x[(size_t)(q0 + q) * DIM + d];
    }
    __syncthreads();

    const int q  = t & (FB_QT - 1);
    const int ln = t >> 4;
    const float myx2 = x2[q0 + q];
    const float4* xp = (const float4*)xs[q];

    float bd0 = FLT_BIG, bd1 = FLT_BIG, bd2 = FLT_BIG, bd3 = FLT_BIG, bd4 = FLT_BIG;
    int   bi0 = -1, bi1 = -1, bi2 = -1, bi3 = -1, bi4 = -1;

    int n = n0 + ln;
    for (; n < n1; n += 16) {
        const float4* r0 = (const float4*)(train + (size_t)n * DIM);
        float dA = 0.f;
#pragma unroll 8
        for (int i = 0; i < DIM / 4; ++i) {
            float4 a = xp[i], b0 = r0[i];
            dA += a.x * b0.x + a.y * b0.y + a.z * b0.z + a.w * b0.w;
        }
        float vA = myx2 - 2.f * dA + t2[n];
        TOP5_INSERT(vA, n);
    }

    rd[q][ln * KNN_K + 0] = bd0;  ri[q][ln * KNN_K + 0] = bi0;
    rd[q][ln * KNN_K + 1] = bd1;  ri[q][ln * KNN_K + 1] = bi1;
    rd[q][ln * KNN_K + 2] = bd2;  ri[q][ln * KNN_K + 2] = bi2;
    rd[q][ln * KNN_K + 3] = bd3;  ri[q][ln * KNN_K + 3] = bi3;
    rd[q][ln * KNN_K + 4] = bd4;  ri[q][ln * KNN_K + 4] = bi4;
    __syncthreads();

    if (t < FB_QT) {
        float* dq = rd[t]; int* iq = ri[t];
        size_t base = ((size_t)(q0 + t) * FB_NCHUNK + chunk) * KNN_K;
#pragma unroll
        for (int k = 0; k < KNN_K; ++k) {
            float best = FLT_BIG; int bj = 0;
            for (int j = 0; j < 16 * KNN_K; ++j) {
                float v = dq[j];
                if (v < best) { best = v; bj = j; }
            }
            cand_d[base + k] = best; cand_i[base + k] = iq[bj];
            dq[bj] = FLT_BIG;
        }
    }
}

__global__ void fb_phaseB(const float* __restrict__ cand_d,
                          const int* __restrict__ cand_i,
                          const float* __restrict__ labels,
                          float* __restrict__ out, int B, int ncand) {
    int qq = blockIdx.x * blockDim.x + threadIdx.x;
    if (qq >= B) return;
    const float* cd = cand_d + (size_t)qq * ncand;
    const int*   ci = cand_i + (size_t)qq * ncand;

    float bd0 = FLT_BIG, bd1 = FLT_BIG, bd2 = FLT_BIG, bd3 = FLT_BIG, bd4 = FLT_BIG;
    int   bi0 = -1, bi1 = -1, bi2 = -1, bi3 = -1, bi4 = -1;
    for (int j = 0; j < ncand; ++j) {
        float v = cd[j]; int id = ci[j];
        TOP5_INSERT(v, id);
    }
    float d0 = sqrtf(fmaxf(bd0, 0.f));
    float d1 = sqrtf(fmaxf(bd1, 0.f));
    float d2 = sqrtf(fmaxf(bd2, 0.f));
    float d3 = sqrtf(fmaxf(bd3, 0.f));
    float d4 = sqrtf(fmaxf(bd4, 0.f));
    bool zero = (d0 == 0.f) || (d1 == 0.f) || (d2 == 0.f) || (d3 == 0.f) || (d4 == 0.f);
    float w0, w1, w2, w3, w4;
    if (zero) {
        w0 = (d0 == 0.f) ? 1.f : 0.f;
        w1 = (d1 == 0.f) ? 1.f : 0.f;
        w2 = (d2 == 0.f) ? 1.f : 0.f;
        w3 = (d3 == 0.f) ? 1.f : 0.f;
        w4 = (d4 == 0.f) ? 1.f : 0.f;
    } else {
        w0 = 1.f / d0; w1 = 1.f / d1; w2 = 1.f / d2; w3 = 1.f / d3; w4 = 1.f / d4;
    }
    float wsum = w0 + w1 + w2 + w3 + w4;
    float lsum = w0 * labels[bi0] + w1 * labels[bi1] + w2 * labels[bi2]
               + w3 * labels[bi3] + w4 * labels[bi4];
    out[qq] = lsum / wsum;
}

// ---------------------------------------------------------------- launch
static inline size_t align256(size_t v) { return (v + 255) & ~(size_t)255; }

extern "C" void kernel_launch(void* const* d_in, const int* in_sizes, int n_in,
                              void* d_out, int out_size, void* d_ws, size_t ws_size,
                              hipStream_t stream) {
    const float* x      = (const float*)d_in[0];   // [B, D] fp32
    const float* train  = (const float*)d_in[1];   // [N, D] fp32
    const float* labels = (const float*)d_in[2];   // [N]    fp32

    const int N = in_sizes[2];
    const int D = in_sizes[1] / N;
    const int B = in_sizes[0] / D;
    (void)n_in;

    size_t o_tbf = 0;
    size_t o_xbf = align256(o_tbf + (size_t)N * DIM * sizeof(ushortT));
    size_t o_t2c = align256(o_xbf + (size_t)B * DIM * sizeof(ushortT));
    size_t o_x2d = align256(o_t2c + (size_t)N * sizeof(float));   // dummy x-norms
    size_t o_ck  = align256(o_x2d + (size_t)B * sizeof(float));
    size_t o_ci  = align256(o_ck + (size_t)B * MF_NCAND * sizeof(uint32));
    size_t need  = align256(o_ci + (size_t)B * MF_NCAND * sizeof(uint32));

    const bool mfma_ok = (N == MF_N) && (D == DIM) && (B == MF_B) && (ws_size >= need);

    if (mfma_ok) {
        ushortT* tbf = (ushortT*)((char*)d_ws + o_tbf);
        ushortT* xbf = (ushortT*)((char*)d_ws + o_xbf);
        float* t2c   = (float*)((char*)d_ws + o_t2c);
        float* x2d   = (float*)((char*)d_ws + o_x2d);
        uint32* cand_k = (uint32*)((char*)d_ws + o_ck);
        uint32* cand_i = (uint32*)((char*)d_ws + o_ci);

        prep_kernel<<<(N + 63) / 64, 256, 0, stream>>>(train, tbf, t2c, N);
        prep_kernel<<<(B + 63) / 64, 256, 0, stream>>>(x, xbf, x2d, B);

        dim3 gridA(MF_NCH, MF_B / MF_QPB);   // chunk-major dispatch
        knn_mfma<<<gridA, 256, 0, stream>>>(xbf, tbf, t2c, cand_k, cand_i);
        knn_final<<<MF_B, 64, 0, stream>>>(cand_k, cand_i, x, train, labels,
                                           (float*)d_out);
    } else {
        float* t2     = (float*)d_ws;
        float* x2v    = t2 + N;
        float* cand_d = x2v + B;
        int*   cand_i = (int*)(cand_d + (size_t)B * FB_NCHUNK * KNN_K);

        rowsq_kernel<<<(N + 255) / 256, 256, 0, stream>>>(train, t2, N);
        rowsq_kernel<<<(B + 255) / 256, 256, 0, stream>>>(x, x2v, B);
        const int chunkSize = (N + FB_NCHUNK - 1) / FB_NCHUNK;
        dim3 gridA(B / FB_QT, FB_NCHUNK);
        fb_phaseA<<<gridA, FB_NT, 0, stream>>>(x, train, x2v, t2,
                                               cand_d, cand_i, N, chunkSize);
        fb_phaseB<<<(B + 255) / 256, 256, 0, stream>>>(cand_d, cand_i, labels,
                                                       (float*)d_out, B,
                                                       FB_NCHUNK * KNN_K);
    }
}